// Round 4
// baseline (96.039 us; speedup 1.0000x reference)
//
#include <hip/hip_runtime.h>
#include <hip/hip_fp16.h>

typedef _Float16 half8 __attribute__((ext_vector_type(8)));
typedef float f32x4 __attribute__((ext_vector_type(4)));

#define B_   8192
#define DIN  2048
#define C_   1000
#define CP   1024
#define NP2  512   // u,v interleaved rows

// ---- workspace layout (bytes) ----
static const size_t OFF_XH  = 0;                                   // xh  [8192][2048] f16
static const size_t OFF_WH  = OFF_XH  + (size_t)B_ * DIN * 2;      // wh  [1024][2048] f16 (rows>=1000 zero)
static const size_t OFF_UVH = OFF_WH  + (size_t)CP * DIN * 2;      // uvh [512][1024]  f16
static const size_t OFF_PH  = OFF_UVH + (size_t)NP2 * CP * 2;      // predsh [8192][1024] f16
static const size_t OFF_SC  = OFF_PH  + (size_t)B_ * CP * 2;       // scores [8192] f32
static const size_t OFF_RS  = OFF_SC  + (size_t)B_ * 4;            // rowsum [8192] f32
static const size_t WS_NEED = OFF_RS  + (size_t)B_ * 4;

__device__ __forceinline__ void gload16(const void* g, void* l) {
  __builtin_amdgcn_global_load_lds(
      (const __attribute__((address_space(1))) void*)g,
      (__attribute__((address_space(3))) void*)l, 16, 0, 0);
}

// ---------------- prep: f32 -> f16 conversions + zeroing ----------------
__global__ __launch_bounds__(256) void prep_kernel(
    const float* __restrict__ x, const float* __restrict__ Wm,
    const float* __restrict__ u, const float* __restrict__ v,
    _Float16* __restrict__ xh, _Float16* __restrict__ wh,
    _Float16* __restrict__ uvh, float* __restrict__ scores,
    float* __restrict__ rowsum)
{
  const long NX  = (long)B_ * DIN / 8;      // 2,097,152
  const long NW  = (long)CP * DIN / 8;      //   262,144
  const long NUV = (long)NP2 * CP / 8;      //    65,536
  const long NZ  = 2 * (long)B_ / 8;        //     2,048
  const long T   = NX + NW + NUV + NZ;
  for (long idx = (long)blockIdx.x * blockDim.x + threadIdx.x; idx < T;
       idx += (long)gridDim.x * blockDim.x) {
    if (idx < NX) {
      long e = idx * 8;
      float4 p0 = *(const float4*)(x + e);
      float4 p1 = *(const float4*)(x + e + 4);
      half8 h;
      h[0] = (_Float16)p0.x; h[1] = (_Float16)p0.y; h[2] = (_Float16)p0.z; h[3] = (_Float16)p0.w;
      h[4] = (_Float16)p1.x; h[5] = (_Float16)p1.y; h[6] = (_Float16)p1.z; h[7] = (_Float16)p1.w;
      *(half8*)(xh + e) = h;
    } else if (idx < NX + NW) {
      long e = (idx - NX) * 8;
      int row = (int)(e >> 11);
      half8 h;
      if (row < C_) {
        float4 p0 = *(const float4*)(Wm + e);
        float4 p1 = *(const float4*)(Wm + e + 4);
        h[0] = (_Float16)p0.x; h[1] = (_Float16)p0.y; h[2] = (_Float16)p0.z; h[3] = (_Float16)p0.w;
        h[4] = (_Float16)p1.x; h[5] = (_Float16)p1.y; h[6] = (_Float16)p1.z; h[7] = (_Float16)p1.w;
      } else {
        h = (half8)(_Float16)0.f;
      }
      *(half8*)(wh + e) = h;
    } else if (idx < NX + NW + NUV) {
      long e = (idx - NX - NW) * 8;
      int j = (int)(e >> 10);
      int k = (int)(e & 1023);
      const float* src = (j & 1) ? v : u;
      int p = j >> 1;
      half8 h;
      #pragma unroll
      for (int t = 0; t < 8; ++t) {
        int kk = k + t;
        h[t] = (kk < C_) ? (_Float16)src[(size_t)p * C_ + kk] : (_Float16)0.f;
      }
      *(half8*)(uvh + e) = h;
    } else {
      long e = (idx - NX - NW - NUV) * 8;
      float4 z = {0.f, 0.f, 0.f, 0.f};
      if (e < B_) {
        *(float4*)(scores + e) = z; *(float4*)(scores + e + 4) = z;
      } else {
        long r = e - B_;
        *(float4*)(rowsum + r) = z; *(float4*)(rowsum + r + 4) = z;
      }
    }
  }
}

// ---------------- main GEMM: preds = xh @ wh^T + bm ----------------
// 256x128 tile, BK=64, 512 threads (8 waves: 2M x 4N, wave tile 128x32).
// Triple-buffered LDS (3 x 48KB): tile t in buf[t%3]; while computing tile t
// we stage tile t+2, and the once-per-K-tile wait is a counted vmcnt(6)
// (tile t+1's 6 loads retire, t+2's 6 stay in flight) -- the T3/T4 pattern.
// 2 phases per K-tile: {ds_read subtile || 3 gload_lds -> barrier ->
// setprio(1) 16 MFMA setprio(0) -> [vmcnt] -> barrier}.
__global__ __launch_bounds__(512) void gemm1_kernel(
    const _Float16* __restrict__ xh, const _Float16* __restrict__ wh,
    const float* __restrict__ bmv, float* __restrict__ preds,
    _Float16* __restrict__ predsh, float* __restrict__ rowsum)
{
  // per buffer: A[256][64] f16 (32KB) at +0, B[128][64] f16 (16KB) at +32768
  __shared__ _Float16 lds[3 * 24576];   // 144 KB
  const int tid  = threadIdx.x;
  const int lane = tid & 63;
  const int w    = tid >> 6;       // 0..7
  const int wm   = w >> 2;         // 0..1 (M half)
  const int wn   = w & 3;          // 0..3 (N quarter)
  const int bm0  = blockIdx.x * 256;
  const int bn0  = blockIdx.y * 128;

  f32x4 acc[8][2] = {};

  // staging sources (pre-swizzled global addr; linear gload_lds dest)
  const _Float16* srcA[4];
  const _Float16* srcB[2];
  #pragma unroll
  for (int k = 0; k < 4; ++k) {
    int slot = k * 512 + tid;
    int row  = slot >> 3;              // 0..255
    int cb   = (slot & 7) << 4;
    int scb  = cb ^ ((row & 7) << 4);
    srcA[k] = xh + (size_t)(bm0 + row) * DIN + (scb >> 1);
  }
  #pragma unroll
  for (int k = 0; k < 2; ++k) {
    int slot = k * 512 + tid;
    int row  = slot >> 3;              // 0..127
    int cb   = (slot & 7) << 4;
    int scb  = cb ^ ((row & 7) << 4);
    srcB[k] = wh + (size_t)(bn0 + row) * DIN + (scb >> 1);
  }

  // ds_read fragment offsets (bytes, within one buffer)
  int aoff[8][2], boff[2][2];
  #pragma unroll
  for (int m = 0; m < 8; ++m) {
    #pragma unroll
    for (int ks = 0; ks < 2; ++ks) {
      int ra = wm * 128 + m * 16 + (lane & 15);
      int kb = ks * 64 + (lane >> 4) * 16;
      aoff[m][ks] = ra * 128 + (kb ^ ((ra & 7) << 4));
    }
  }
  #pragma unroll
  for (int n = 0; n < 2; ++n) {
    #pragma unroll
    for (int ks = 0; ks < 2; ++ks) {
      int rb = wn * 32 + n * 16 + (lane & 15);
      int kb = ks * 64 + (lane >> 4) * 16;
      boff[n][ks] = 32768 + rb * 128 + (kb ^ ((rb & 7) << 4));
    }
  }

  auto stageSet = [&](int b, int which) {   // which: 0..3 = A sets, 4..5 = B sets
    char* base = (char*)lds + b * 49152;
    if (which < 4) gload16(srcA[which], base + which * 8192 + w * 1024);
    else           gload16(srcB[which - 4], base + 32768 + (which - 4) * 8192 + w * 1024);
  };
  auto advance = [&]() {
    #pragma unroll
    for (int k = 0; k < 4; ++k) srcA[k] += 64;
    #pragma unroll
    for (int k = 0; k < 2; ++k) srcB[k] += 64;
  };

  const int NT = DIN / 64;   // 32

  // prologue: stage tile0 -> buf0, tile1 -> buf1 (12 loads in flight)
  #pragma unroll
  for (int q = 0; q < 6; ++q) stageSet(0, q);
  advance();
  #pragma unroll
  for (int q = 0; q < 6; ++q) stageSet(1, q);
  advance();
  asm volatile("s_waitcnt vmcnt(6)" ::: "memory");   // tile0 staged
  __builtin_amdgcn_s_barrier();
  asm volatile("" ::: "memory");

  int c = 0;
  #pragma unroll 1
  for (int t = 0; t < NT; ++t) {
    const char* bufc = (const char*)lds + c * 49152;
    int sb = c - 1; if (sb < 0) sb = 2;              // (c+2)%3
    const bool st = (t + 2 < NT);

    // ---- phase 0: A m-frags 0..3 + all B frags; stage sets 0..2 ----
    half8 a2[4][2], b2[2][2];
    #pragma unroll
    for (int m = 0; m < 4; ++m)
      #pragma unroll
      for (int ks = 0; ks < 2; ++ks)
        a2[m][ks] = *(const half8*)(bufc + aoff[m][ks]);
    #pragma unroll
    for (int n = 0; n < 2; ++n)
      #pragma unroll
      for (int ks = 0; ks < 2; ++ks)
        b2[n][ks] = *(const half8*)(bufc + boff[n][ks]);
    if (st) { stageSet(sb, 0); stageSet(sb, 1); stageSet(sb, 2); }
    __builtin_amdgcn_s_barrier();
    asm volatile("" ::: "memory");
    __builtin_amdgcn_s_setprio(1);
    #pragma unroll
    for (int m = 0; m < 4; ++m)
      #pragma unroll
      for (int n = 0; n < 2; ++n)
        #pragma unroll
        for (int ks = 0; ks < 2; ++ks)
          acc[m][n] = __builtin_amdgcn_mfma_f32_16x16x32_f16(a2[m][ks], b2[n][ks], acc[m][n], 0, 0, 0);
    __builtin_amdgcn_s_setprio(0);
    __builtin_amdgcn_s_barrier();
    asm volatile("" ::: "memory");

    // ---- phase 1: A m-frags 4..7; stage sets 3..5 ----
    #pragma unroll
    for (int m = 0; m < 4; ++m)
      #pragma unroll
      for (int ks = 0; ks < 2; ++ks)
        a2[m][ks] = *(const half8*)(bufc + aoff[m + 4][ks]);
    if (st) { stageSet(sb, 3); stageSet(sb, 4); stageSet(sb, 5); advance(); }
    __builtin_amdgcn_s_barrier();
    asm volatile("" ::: "memory");
    __builtin_amdgcn_s_setprio(1);
    #pragma unroll
    for (int m = 0; m < 4; ++m)
      #pragma unroll
      for (int n = 0; n < 2; ++n)
        #pragma unroll
        for (int ks = 0; ks < 2; ++ks)
          acc[m + 4][n] = __builtin_amdgcn_mfma_f32_16x16x32_f16(a2[m][ks], b2[n][ks], acc[m + 4][n], 0, 0, 0);
    __builtin_amdgcn_s_setprio(0);
    // once-per-K-tile wait: tile t+1 must be resident before next iter reads it
    if (st)                 asm volatile("s_waitcnt vmcnt(6)" ::: "memory");
    else if (t + 1 < NT)    asm volatile("s_waitcnt vmcnt(0)" ::: "memory");
    __builtin_amdgcn_s_barrier();
    asm volatile("" ::: "memory");

    c = (c == 2) ? 0 : c + 1;
  }

  // epilogue: bias add, f32 preds, f16 predsh, rowsum partials
  float rp[8][4] = {};
  #pragma unroll
  for (int m = 0; m < 8; ++m) {
    #pragma unroll
    for (int n = 0; n < 2; ++n) {
      f32x4 d = acc[m][n];
      int gc = bn0 + wn * 32 + n * 16 + (lane & 15);
      float bias = (gc < C_) ? bmv[gc] : 0.f;
      #pragma unroll
      for (int j = 0; j < 4; ++j) {
        int gr = bm0 + wm * 128 + m * 16 + (lane >> 4) * 4 + j;
        float val = d[j] + bias;
        predsh[(size_t)gr * CP + gc] = (_Float16)val;
        if (gc < C_) preds[(size_t)gr * C_ + gc] = val;
        rp[m][j] += val;
      }
    }
  }
  #pragma unroll
  for (int m = 0; m < 8; ++m) {
    #pragma unroll
    for (int j = 0; j < 4; ++j) {
      float s = rp[m][j];
      s += __shfl_xor(s, 1); s += __shfl_xor(s, 2);
      s += __shfl_xor(s, 4); s += __shfl_xor(s, 8);
      if ((lane & 15) == 0) {
        int gr = bm0 + wm * 128 + m * 16 + (lane >> 4) * 4 + j;
        atomicAdd(&rowsum[gr], s);
      }
    }
  }
}

// ---------------- gating GEMM: scores partials (r2-validated) ----------------
__global__ __launch_bounds__(256) void gemm2_kernel(
    const _Float16* __restrict__ predsh, const _Float16* __restrict__ uvh,
    const float* __restrict__ wv, float* __restrict__ scores)
{
  __shared__ _Float16 sA[2][64 * 64];
  __shared__ _Float16 sB[2][128 * 64];
  const int tid  = threadIdx.x;
  const int lane = tid & 63;
  const int w    = tid >> 6;
  const int wm   = w >> 1, wn = w & 1;   // wave owns 32x64
  const int bm0  = blockIdx.x * 64;
  const int bn0  = blockIdx.y * 128;

  f32x4 acc[2][4] = {};

  const _Float16* srcA[2]; const _Float16* srcB[4];
  #pragma unroll
  for (int i = 0; i < 2; ++i) {
    int slot = i * 256 + tid;
    int row  = slot >> 3;
    int cb   = (slot & 7) << 4;
    int scb  = cb ^ ((row & 7) << 4);
    srcA[i] = predsh + (size_t)(bm0 + row) * CP + (scb >> 1);
  }
  #pragma unroll
  for (int i = 0; i < 4; ++i) {
    int slot = i * 256 + tid;
    int row  = slot >> 3;
    int cb   = (slot & 7) << 4;
    int scb  = cb ^ ((row & 7) << 4);
    srcB[i] = uvh + (size_t)(bn0 + row) * CP + (scb >> 1);
  }
  int aoff[2][2], boff[4][2];
  #pragma unroll
  for (int ks = 0; ks < 2; ++ks) {
    int kb = ks * 64 + (lane >> 4) * 16;
    #pragma unroll
    for (int mi = 0; mi < 2; ++mi) {
      int ra = wm * 32 + mi * 16 + (lane & 15);
      aoff[mi][ks] = ra * 128 + (kb ^ ((ra & 7) << 4));
    }
    #pragma unroll
    for (int ni = 0; ni < 4; ++ni) {
      int rb = wn * 64 + ni * 16 + (lane & 15);
      boff[ni][ks] = rb * 128 + (kb ^ ((rb & 7) << 4));
    }
  }

  auto stage = [&](int c) {
    #pragma unroll
    for (int i = 0; i < 2; ++i) {
      gload16(srcA[i], &sA[c][(i * 4 + w) * 512]);
      srcA[i] += 64;
    }
    #pragma unroll
    for (int i = 0; i < 4; ++i) {
      gload16(srcB[i], &sB[c][(i * 4 + w) * 512]);
      srcB[i] += 64;
    }
  };

  auto compute = [&](int c) {
    const char* bA = (const char*)&sA[c][0];
    const char* bB = (const char*)&sB[c][0];
    #pragma unroll
    for (int ks = 0; ks < 2; ++ks) {
      half8 a[2], b[4];
      #pragma unroll
      for (int mi = 0; mi < 2; ++mi) a[mi] = *(const half8*)(bA + aoff[mi][ks]);
      #pragma unroll
      for (int ni = 0; ni < 4; ++ni) b[ni] = *(const half8*)(bB + boff[ni][ks]);
      #pragma unroll
      for (int mi = 0; mi < 2; ++mi)
        #pragma unroll
        for (int ni = 0; ni < 4; ++ni)
          acc[mi][ni] = __builtin_amdgcn_mfma_f32_16x16x32_f16(a[mi], b[ni], acc[mi][ni], 0, 0, 0);
    }
  };

  const int NT = CP / 64;   // 16
  stage(0);
  #pragma unroll 1
  for (int kt = 0; kt < NT; kt += 2) {
    stage(1);
    asm volatile("s_waitcnt vmcnt(6)" ::: "memory");
    __builtin_amdgcn_s_barrier();
    asm volatile("" ::: "memory");
    compute(0);
    __builtin_amdgcn_s_barrier();
    asm volatile("" ::: "memory");
    if (kt + 2 < NT) {
      stage(0);
      asm volatile("s_waitcnt vmcnt(6)" ::: "memory");
    } else {
      asm volatile("s_waitcnt vmcnt(0)" ::: "memory");
    }
    __builtin_amdgcn_s_barrier();
    asm volatile("" ::: "memory");
    compute(1);
    __builtin_amdgcn_s_barrier();
    asm volatile("" ::: "memory");
  }

  float sp[2][4] = {};
  #pragma unroll
  for (int mi = 0; mi < 2; ++mi) {
    #pragma unroll
    for (int ni = 0; ni < 4; ++ni) {
      f32x4 d = acc[mi][ni];
      int gc = bn0 + wn * 64 + ni * 16 + (lane & 15);   // even=u col, odd=v col
      float wq = wv[gc >> 1];
      bool even = ((gc & 1) == 0);
      #pragma unroll
      for (int j = 0; j < 4; ++j) {
        float t  = d[j];
        float pr = __shfl_xor(t, 1);
        float th = 2.f / (1.f + __expf(-2.f * t)) - 1.f;
        float sg = 1.f / (1.f + __expf(-pr));
        sp[mi][j] += even ? (th * sg * wq) : 0.f;
      }
    }
  }
  #pragma unroll
  for (int mi = 0; mi < 2; ++mi) {
    #pragma unroll
    for (int j = 0; j < 4; ++j) {
      float s = sp[mi][j];
      s += __shfl_xor(s, 1); s += __shfl_xor(s, 2);
      s += __shfl_xor(s, 4); s += __shfl_xor(s, 8);
      if ((lane & 15) == 0) {
        int gr = bm0 + wm * 32 + mi * 16 + (lane >> 4) * 4 + j;
        atomicAdd(&scores[gr], s);
      }
    }
  }
}

// ---------------- final: softmax over scores, weighted rowsum ----------------
__global__ __launch_bounds__(1024) void final_kernel(
    const float* __restrict__ scores, const float* __restrict__ rowsum,
    float* __restrict__ out)
{
  __shared__ float red[16], red2[16];
  const int t = threadIdx.x;
  const int lane = t & 63, wid = t >> 6;
  float s[8];
  float m = -3.4e38f;
  #pragma unroll
  for (int i = 0; i < 8; ++i) { s[i] = scores[t + i * 1024]; m = fmaxf(m, s[i]); }
  #pragma unroll
  for (int off = 1; off < 64; off <<= 1) m = fmaxf(m, __shfl_xor(m, off));
  if (lane == 0) red[wid] = m;
  __syncthreads();
  #pragma unroll
  for (int i = 0; i < 16; ++i) m = fmaxf(m, red[i]);
  __syncthreads();

  float se = 0.f, sr = 0.f;
  #pragma unroll
  for (int i = 0; i < 8; ++i) {
    float e = __expf(s[i] - m);
    se += e;
    sr += e * rowsum[t + i * 1024];
  }
  #pragma unroll
  for (int off = 1; off < 64; off <<= 1) { se += __shfl_xor(se, off); sr += __shfl_xor(sr, off); }
  if (lane == 0) { red[wid] = se; red2[wid] = sr; }
  __syncthreads();
  if (t == 0) {
    float tse = 0.f, tsr = 0.f;
    for (int i = 0; i < 16; ++i) { tse += red[i]; tsr += red2[i]; }
    out[0] = tsr / tse;
  }
}

extern "C" void kernel_launch(void* const* d_in, const int* in_sizes, int n_in,
                              void* d_out, int out_size, void* d_ws, size_t ws_size,
                              hipStream_t stream)
{
  const float* x   = (const float*)d_in[0];
  const float* Wm  = (const float*)d_in[1];
  const float* bmv = (const float*)d_in[2];
  const float* u   = (const float*)d_in[3];
  const float* v   = (const float*)d_in[4];
  const float* wv  = (const float*)d_in[5];
  float* out = (float*)d_out;

  if (ws_size < WS_NEED) return;

  char* ws = (char*)d_ws;
  _Float16* xh     = (_Float16*)(ws + OFF_XH);
  _Float16* wh     = (_Float16*)(ws + OFF_WH);
  _Float16* uvh    = (_Float16*)(ws + OFF_UVH);
  _Float16* predsh = (_Float16*)(ws + OFF_PH);
  float*    scores = (float*)(ws + OFF_SC);
  float*    rowsum = (float*)(ws + OFF_RS);

  prep_kernel<<<2048, 256, 0, stream>>>(x, Wm, u, v, xh, wh, uvh, scores, rowsum);
  gemm1_kernel<<<dim3(32, 8), 512, 0, stream>>>(xh, wh, bmv, out, predsh, rowsum);
  gemm2_kernel<<<dim3(128, 4), 256, 0, stream>>>(predsh, uvh, wv, scores);
  final_kernel<<<1, 1024, 0, stream>>>(scores, rowsum, out + (size_t)B_ * C_);
}

// Round 5
// 90.411 us; speedup vs baseline: 1.0623x; 1.0623x over previous
//
#include <hip/hip_runtime.h>
#include <hip/hip_fp16.h>

typedef _Float16 half8 __attribute__((ext_vector_type(8)));
typedef float f32x4 __attribute__((ext_vector_type(4)));

#define B_   8192
#define DIN  2048
#define C_   1000
#define CP   1024
#define NP2  512   // u,v interleaved rows

// ---- workspace layout (bytes) ----
static const size_t OFF_XH  = 0;                                   // xh  [8192][2048] f16
static const size_t OFF_WH  = OFF_XH  + (size_t)B_ * DIN * 2;      // wh  [1024][2048] f16 (rows>=1000 zero)
static const size_t OFF_UVH = OFF_WH  + (size_t)CP * DIN * 2;      // uvh [512][1024]  f16
static const size_t OFF_PH  = OFF_UVH + (size_t)NP2 * CP * 2;      // predsh [8192][1024] f16
static const size_t OFF_SC  = OFF_PH  + (size_t)B_ * CP * 2;       // scores [8192] f32
static const size_t OFF_RS  = OFF_SC  + (size_t)B_ * 4;            // rowsum [8192] f32
static const size_t WS_NEED = OFF_RS  + (size_t)B_ * 4;

#define FENCE asm volatile("" ::: "memory")
#define BARRIER do { FENCE; __builtin_amdgcn_s_barrier(); FENCE; } while (0)

__device__ __forceinline__ void gload16(const void* g, void* l) {
  __builtin_amdgcn_global_load_lds(
      (const __attribute__((address_space(1))) void*)g,
      (__attribute__((address_space(3))) void*)l, 16, 0, 0);
}

// ---------------- prep: f32 -> f16 conversions + zeroing ----------------
__global__ __launch_bounds__(256) void prep_kernel(
    const float* __restrict__ x, const float* __restrict__ Wm,
    const float* __restrict__ u, const float* __restrict__ v,
    _Float16* __restrict__ xh, _Float16* __restrict__ wh,
    _Float16* __restrict__ uvh, float* __restrict__ scores,
    float* __restrict__ rowsum)
{
  const long NX  = (long)B_ * DIN / 8;
  const long NW  = (long)CP * DIN / 8;
  const long NUV = (long)NP2 * CP / 8;
  const long NZ  = 2 * (long)B_ / 8;
  const long T   = NX + NW + NUV + NZ;
  for (long idx = (long)blockIdx.x * blockDim.x + threadIdx.x; idx < T;
       idx += (long)gridDim.x * blockDim.x) {
    if (idx < NX) {
      long e = idx * 8;
      float4 p0 = *(const float4*)(x + e);
      float4 p1 = *(const float4*)(x + e + 4);
      half8 h;
      h[0] = (_Float16)p0.x; h[1] = (_Float16)p0.y; h[2] = (_Float16)p0.z; h[3] = (_Float16)p0.w;
      h[4] = (_Float16)p1.x; h[5] = (_Float16)p1.y; h[6] = (_Float16)p1.z; h[7] = (_Float16)p1.w;
      *(half8*)(xh + e) = h;
    } else if (idx < NX + NW) {
      long e = (idx - NX) * 8;
      int row = (int)(e >> 11);
      half8 h;
      if (row < C_) {
        float4 p0 = *(const float4*)(Wm + e);
        float4 p1 = *(const float4*)(Wm + e + 4);
        h[0] = (_Float16)p0.x; h[1] = (_Float16)p0.y; h[2] = (_Float16)p0.z; h[3] = (_Float16)p0.w;
        h[4] = (_Float16)p1.x; h[5] = (_Float16)p1.y; h[6] = (_Float16)p1.z; h[7] = (_Float16)p1.w;
      } else {
        h = (half8)(_Float16)0.f;
      }
      *(half8*)(wh + e) = h;
    } else if (idx < NX + NW + NUV) {
      long e = (idx - NX - NW) * 8;
      int j = (int)(e >> 10);
      int k = (int)(e & 1023);
      const float* src = (j & 1) ? v : u;
      int p = j >> 1;
      half8 h;
      #pragma unroll
      for (int t = 0; t < 8; ++t) {
        int kk = k + t;
        h[t] = (kk < C_) ? (_Float16)src[(size_t)p * C_ + kk] : (_Float16)0.f;
      }
      *(half8*)(uvh + e) = h;
    } else {
      long e = (idx - NX - NW - NUV) * 8;
      float4 z = {0.f, 0.f, 0.f, 0.f};
      if (e < B_) {
        *(float4*)(scores + e) = z; *(float4*)(scores + e + 4) = z;
      } else {
        long r = e - B_;
        *(float4*)(rowsum + r) = z; *(float4*)(rowsum + r + 4) = z;
      }
    }
  }
}

// ---------------- main GEMM: preds = xh @ wh^T + bm ----------------
// 256x128 tile, BK=64, 512 threads = 8 waves (4M x 2N), wave tile 64x64.
// 3-buffer LDS (3 x 48KB). 4 phases per K-tile, each phase:
//   {4 ds_read_b128 (for NEXT phase's MFMA) || 1-2 global_load_lds -> barrier
//    -> setprio(1) 8 MFMA setprio(0)}.
// Fragment register reuse: P0 reads A-high(t), P1 reads B-high(t),
// P2 reads A-low(t+1), P3 reads B-low(t+1) -- every ds_read has a full
// phase of latency slack, so the LDS pipe overlaps the MFMA regions.
// vmcnt(4) once per K-tile (FIFO: t+1's 6 loads retire, t+2's 4 in flight).
__global__ __launch_bounds__(512) void gemm1_kernel(
    const _Float16* __restrict__ xh, const _Float16* __restrict__ wh,
    const float* __restrict__ bmv, float* __restrict__ preds,
    _Float16* __restrict__ predsh, float* __restrict__ rowsum)
{
  // per buffer: A[256][64] f16 (32KB) @ +0, B[128][64] f16 (16KB) @ +32768
  __shared__ _Float16 lds[3 * 24576];   // 144 KB
  const int tid  = threadIdx.x;
  const int lane = tid & 63;
  const int w    = tid >> 6;       // 0..7
  const int wm   = w >> 1;         // 0..3 (M quarter, 64 rows)
  const int wn   = w & 1;          // 0..1 (N half, 64 cols)
  const int bm0  = blockIdx.x * 256;
  const int bn0  = blockIdx.y * 128;

  f32x4 acc[4][4] = {};

  // staging sources (pre-swizzled global addr; linear gload_lds dest)
  const _Float16* srcA[4];
  const _Float16* srcB[2];
  #pragma unroll
  for (int k = 0; k < 4; ++k) {
    int slot = k * 512 + tid;
    int row  = slot >> 3;              // 0..255
    int cb   = (slot & 7) << 4;
    int scb  = cb ^ ((row & 7) << 4);
    srcA[k] = xh + (size_t)(bm0 + row) * DIN + (scb >> 1);
  }
  #pragma unroll
  for (int k = 0; k < 2; ++k) {
    int slot = k * 512 + tid;
    int row  = slot >> 3;              // 0..127
    int cb   = (slot & 7) << 4;
    int scb  = cb ^ ((row & 7) << 4);
    srcB[k] = wh + (size_t)(bn0 + row) * DIN + (scb >> 1);
  }

  // ds_read fragment byte offsets within one buffer
  int aoff[4][2], boff[4][2];
  #pragma unroll
  for (int m = 0; m < 4; ++m) {
    #pragma unroll
    for (int ks = 0; ks < 2; ++ks) {
      int ra = wm * 64 + m * 16 + (lane & 15);
      int kb = ks * 64 + (lane >> 4) * 16;
      aoff[m][ks] = ra * 128 + (kb ^ ((ra & 7) << 4));
    }
  }
  #pragma unroll
  for (int n = 0; n < 4; ++n) {
    #pragma unroll
    for (int ks = 0; ks < 2; ++ks) {
      int rb = wn * 64 + n * 16 + (lane & 15);
      int kb = ks * 64 + (lane >> 4) * 16;
      boff[n][ks] = 32768 + rb * 128 + (kb ^ ((rb & 7) << 4));
    }
  }

  // fragment registers: A-low double-buffered across tiles (aLa/aLb),
  // A-high / B-low / B-high single-set (read-after-last-use timing).
  half8 aLa[2][2], aLb[2][2], aHf[2][2], bLf[2][2], bHf[2][2];

  auto stA = [&](int cs, int k) {
    gload16(srcA[k], (char*)lds + cs * 49152 + k * 8192 + w * 1024);
  };
  auto stB = [&](int cs, int k) {
    gload16(srcB[k], (char*)lds + cs * 49152 + 32768 + k * 8192 + w * 1024);
  };
  auto advance = [&]() {
    #pragma unroll
    for (int k = 0; k < 4; ++k) srcA[k] += 64;
    srcB[0] += 64; srcB[1] += 64;
  };
  auto rdAH = [&](const char* b) {
    #pragma unroll
    for (int m = 0; m < 2; ++m)
      #pragma unroll
      for (int ks = 0; ks < 2; ++ks)
        aHf[m][ks] = *(const half8*)(b + aoff[m + 2][ks]);
  };
  auto rdBH = [&](const char* b) {
    #pragma unroll
    for (int n = 0; n < 2; ++n)
      #pragma unroll
      for (int ks = 0; ks < 2; ++ks)
        bHf[n][ks] = *(const half8*)(b + boff[n + 2][ks]);
  };
  auto rdAL = [&](const char* b, half8 (&d)[2][2]) {
    #pragma unroll
    for (int m = 0; m < 2; ++m)
      #pragma unroll
      for (int ks = 0; ks < 2; ++ks)
        d[m][ks] = *(const half8*)(b + aoff[m][ks]);
  };
  auto rdBL = [&](const char* b) {
    #pragma unroll
    for (int n = 0; n < 2; ++n)
      #pragma unroll
      for (int ks = 0; ks < 2; ++ks)
        bLf[n][ks] = *(const half8*)(b + boff[n][ks]);
  };
  auto mfLL = [&](half8 (&aL)[2][2]) {
    #pragma unroll
    for (int m = 0; m < 2; ++m)
      #pragma unroll
      for (int n = 0; n < 2; ++n)
        #pragma unroll
        for (int ks = 0; ks < 2; ++ks)
          acc[m][n] = __builtin_amdgcn_mfma_f32_16x16x32_f16(aL[m][ks], bLf[n][ks], acc[m][n], 0, 0, 0);
  };
  auto mfHL = [&]() {
    #pragma unroll
    for (int m = 0; m < 2; ++m)
      #pragma unroll
      for (int n = 0; n < 2; ++n)
        #pragma unroll
        for (int ks = 0; ks < 2; ++ks)
          acc[m + 2][n] = __builtin_amdgcn_mfma_f32_16x16x32_f16(aHf[m][ks], bLf[n][ks], acc[m + 2][n], 0, 0, 0);
  };
  auto mfLH = [&](half8 (&aL)[2][2]) {
    #pragma unroll
    for (int m = 0; m < 2; ++m)
      #pragma unroll
      for (int n = 0; n < 2; ++n)
        #pragma unroll
        for (int ks = 0; ks < 2; ++ks)
          acc[m][n + 2] = __builtin_amdgcn_mfma_f32_16x16x32_f16(aL[m][ks], bHf[n][ks], acc[m][n + 2], 0, 0, 0);
  };
  auto mfHH = [&]() {
    #pragma unroll
    for (int m = 0; m < 2; ++m)
      #pragma unroll
      for (int n = 0; n < 2; ++n)
        #pragma unroll
        for (int ks = 0; ks < 2; ++ks)
          acc[m + 2][n + 2] = __builtin_amdgcn_mfma_f32_16x16x32_f16(aHf[m][ks], bHf[n][ks], acc[m + 2][n + 2], 0, 0, 0);
  };

  // ---- prologue: stage tile0 -> buf0, tile1 -> buf1 ----
  #pragma unroll
  for (int k = 0; k < 4; ++k) stA(0, k);
  stB(0, 0); stB(0, 1);
  advance();
  #pragma unroll
  for (int k = 0; k < 4; ++k) stA(1, k);
  stB(1, 0); stB(1, 1);
  advance();
  asm volatile("s_waitcnt vmcnt(6)" ::: "memory");   // tile0 resident
  BARRIER;
  rdAL((const char*)lds, aLa);
  rdBL((const char*)lds);

  // ---- main loop: tiles 0..29, two per iteration ----
  int c0 = 0;
  #pragma unroll 1
  for (int t = 0; t < 30; t += 2) {
    const int c1 = (c0 == 2) ? 0 : c0 + 1;
    const int c2 = (c1 == 2) ? 0 : c1 + 1;
    const char* bt  = (const char*)lds + c0 * 49152;
    const char* bn1 = (const char*)lds + c1 * 49152;
    const char* bn2 = (const char*)lds + c2 * 49152;

    // ===== even tile t (current A-low = aLa) =====
    rdAH(bt);  stA(c2, 0); stA(c2, 1);                 // P0
    BARRIER;
    __builtin_amdgcn_s_setprio(1); mfLL(aLa); __builtin_amdgcn_s_setprio(0);

    rdBH(bt);  stA(c2, 2); stA(c2, 3);                 // P1
    asm volatile("s_waitcnt vmcnt(4)" ::: "memory");   // tile t+1 resident
    BARRIER;
    __builtin_amdgcn_s_setprio(1); mfHL(); __builtin_amdgcn_s_setprio(0);

    rdAL(bn1, aLb);  stB(c2, 0);                       // P2 (prefetch t+1 A-low)
    BARRIER;
    __builtin_amdgcn_s_setprio(1); mfLH(aLa); __builtin_amdgcn_s_setprio(0);

    rdBL(bn1);  stB(c2, 1); advance();                 // P3 (prefetch t+1 B-low)
    BARRIER;
    __builtin_amdgcn_s_setprio(1); mfHH(); __builtin_amdgcn_s_setprio(0);

    // ===== odd tile t+1 (current A-low = aLb) =====
    rdAH(bn1);  stA(c0, 0); stA(c0, 1);                // stage tile t+3 -> buf c0
    BARRIER;
    __builtin_amdgcn_s_setprio(1); mfLL(aLb); __builtin_amdgcn_s_setprio(0);

    rdBH(bn1);  stA(c0, 2); stA(c0, 3);
    asm volatile("s_waitcnt vmcnt(4)" ::: "memory");   // tile t+2 resident
    BARRIER;
    __builtin_amdgcn_s_setprio(1); mfHL(); __builtin_amdgcn_s_setprio(0);

    rdAL(bn2, aLa);  stB(c0, 0);                       // prefetch t+2 A-low
    BARRIER;
    __builtin_amdgcn_s_setprio(1); mfLH(aLb); __builtin_amdgcn_s_setprio(0);

    rdBL(bn2);  stB(c0, 1); advance();                 // prefetch t+2 B-low
    BARRIER;
    __builtin_amdgcn_s_setprio(1); mfHH(); __builtin_amdgcn_s_setprio(0);

    c0 = c2;
  }

  // ---- tail: tile 30 (buf0, cur aLa; prefetch tile31 from buf1) ----
  {
    const char* bt  = (const char*)lds;
    const char* bn1 = (const char*)lds + 49152;
    rdAH(bt);
    BARRIER;
    __builtin_amdgcn_s_setprio(1); mfLL(aLa); __builtin_amdgcn_s_setprio(0);
    rdBH(bt);
    asm volatile("s_waitcnt vmcnt(0)" ::: "memory");   // tile31 resident
    BARRIER;
    __builtin_amdgcn_s_setprio(1); mfHL(); __builtin_amdgcn_s_setprio(0);
    rdAL(bn1, aLb);
    BARRIER;
    __builtin_amdgcn_s_setprio(1); mfLH(aLa); __builtin_amdgcn_s_setprio(0);
    rdBL(bn1);
    BARRIER;
    __builtin_amdgcn_s_setprio(1); mfHH(); __builtin_amdgcn_s_setprio(0);
    // ---- tile 31 (buf1, cur aLb): no barriers needed ----
    rdAH(bn1); rdBH(bn1);
    mfLL(aLb); mfHL(); mfLH(aLb); mfHH();
  }

  // ---- epilogue: bias add, f32 preds, f16 predsh, rowsum partials ----
  float rp[4][4] = {};
  #pragma unroll
  for (int m = 0; m < 4; ++m) {
    #pragma unroll
    for (int n = 0; n < 4; ++n) {
      f32x4 d = acc[m][n];
      int gc = bn0 + wn * 64 + n * 16 + (lane & 15);
      float bias = (gc < C_) ? bmv[gc] : 0.f;
      #pragma unroll
      for (int j = 0; j < 4; ++j) {
        int gr = bm0 + wm * 64 + m * 16 + (lane >> 4) * 4 + j;
        float val = d[j] + bias;
        predsh[(size_t)gr * CP + gc] = (_Float16)val;
        if (gc < C_) preds[(size_t)gr * C_ + gc] = val;
        rp[m][j] += val;
      }
    }
  }
  #pragma unroll
  for (int m = 0; m < 4; ++m) {
    #pragma unroll
    for (int j = 0; j < 4; ++j) {
      float s = rp[m][j];
      s += __shfl_xor(s, 1); s += __shfl_xor(s, 2);
      s += __shfl_xor(s, 4); s += __shfl_xor(s, 8);
      if ((lane & 15) == 0) {
        int gr = bm0 + wm * 64 + m * 16 + (lane >> 4) * 4 + j;
        atomicAdd(&rowsum[gr], s);
      }
    }
  }
}

// ---------------- gating GEMM: scores partials (r2-validated) ----------------
__global__ __launch_bounds__(256) void gemm2_kernel(
    const _Float16* __restrict__ predsh, const _Float16* __restrict__ uvh,
    const float* __restrict__ wv, float* __restrict__ scores)
{
  __shared__ _Float16 sA[2][64 * 64];
  __shared__ _Float16 sB[2][128 * 64];
  const int tid  = threadIdx.x;
  const int lane = tid & 63;
  const int w    = tid >> 6;
  const int wm   = w >> 1, wn = w & 1;   // wave owns 32x64
  const int bm0  = blockIdx.x * 64;
  const int bn0  = blockIdx.y * 128;

  f32x4 acc[2][4] = {};

  const _Float16* srcA[2]; const _Float16* srcB[4];
  #pragma unroll
  for (int i = 0; i < 2; ++i) {
    int slot = i * 256 + tid;
    int row  = slot >> 3;
    int cb   = (slot & 7) << 4;
    int scb  = cb ^ ((row & 7) << 4);
    srcA[i] = predsh + (size_t)(bm0 + row) * CP + (scb >> 1);
  }
  #pragma unroll
  for (int i = 0; i < 4; ++i) {
    int slot = i * 256 + tid;
    int row  = slot >> 3;
    int cb   = (slot & 7) << 4;
    int scb  = cb ^ ((row & 7) << 4);
    srcB[i] = uvh + (size_t)(bn0 + row) * CP + (scb >> 1);
  }
  int aoff[2][2], boff[4][2];
  #pragma unroll
  for (int ks = 0; ks < 2; ++ks) {
    int kb = ks * 64 + (lane >> 4) * 16;
    #pragma unroll
    for (int mi = 0; mi < 2; ++mi) {
      int ra = wm * 32 + mi * 16 + (lane & 15);
      aoff[mi][ks] = ra * 128 + (kb ^ ((ra & 7) << 4));
    }
    #pragma unroll
    for (int ni = 0; ni < 4; ++ni) {
      int rb = wn * 64 + ni * 16 + (lane & 15);
      boff[ni][ks] = rb * 128 + (kb ^ ((rb & 7) << 4));
    }
  }

  auto stage = [&](int c) {
    #pragma unroll
    for (int i = 0; i < 2; ++i) {
      gload16(srcA[i], &sA[c][(i * 4 + w) * 512]);
      srcA[i] += 64;
    }
    #pragma unroll
    for (int i = 0; i < 4; ++i) {
      gload16(srcB[i], &sB[c][(i * 4 + w) * 512]);
      srcB[i] += 64;
    }
  };

  auto compute = [&](int c) {
    const char* bA = (const char*)&sA[c][0];
    const char* bB = (const char*)&sB[c][0];
    #pragma unroll
    for (int ks = 0; ks < 2; ++ks) {
      half8 a[2], b[4];
      #pragma unroll
      for (int mi = 0; mi < 2; ++mi) a[mi] = *(const half8*)(bA + aoff[mi][ks]);
      #pragma unroll
      for (int ni = 0; ni < 4; ++ni) b[ni] = *(const half8*)(bB + boff[ni][ks]);
      #pragma unroll
      for (int mi = 0; mi < 2; ++mi)
        #pragma unroll
        for (int ni = 0; ni < 4; ++ni)
          acc[mi][ni] = __builtin_amdgcn_mfma_f32_16x16x32_f16(a[mi], b[ni], acc[mi][ni], 0, 0, 0);
    }
  };

  const int NT = CP / 64;   // 16
  stage(0);
  #pragma unroll 1
  for (int kt = 0; kt < NT; kt += 2) {
    stage(1);
    asm volatile("s_waitcnt vmcnt(6)" ::: "memory");
    BARRIER;
    compute(0);
    BARRIER;
    if (kt + 2 < NT) {
      stage(0);
      asm volatile("s_waitcnt vmcnt(6)" ::: "memory");
    } else {
      asm volatile("s_waitcnt vmcnt(0)" ::: "memory");
    }
    BARRIER;
    compute(1);
    BARRIER;
  }

  float sp[2][4] = {};
  #pragma unroll
  for (int mi = 0; mi < 2; ++mi) {
    #pragma unroll
    for (int ni = 0; ni < 4; ++ni) {
      f32x4 d = acc[mi][ni];
      int gc = bn0 + wn * 64 + ni * 16 + (lane & 15);   // even=u col, odd=v col
      float wq = wv[gc >> 1];
      bool even = ((gc & 1) == 0);
      #pragma unroll
      for (int j = 0; j < 4; ++j) {
        float t  = d[j];
        float pr = __shfl_xor(t, 1);
        float th = 2.f / (1.f + __expf(-2.f * t)) - 1.f;
        float sg = 1.f / (1.f + __expf(-pr));
        sp[mi][j] += even ? (th * sg * wq) : 0.f;
      }
    }
  }
  #pragma unroll
  for (int mi = 0; mi < 2; ++mi) {
    #pragma unroll
    for (int j = 0; j < 4; ++j) {
      float s = sp[mi][j];
      s += __shfl_xor(s, 1); s += __shfl_xor(s, 2);
      s += __shfl_xor(s, 4); s += __shfl_xor(s, 8);
      if ((lane & 15) == 0) {
        int gr = bm0 + wm * 32 + mi * 16 + (lane >> 4) * 4 + j;
        atomicAdd(&scores[gr], s);
      }
    }
  }
}

// ---------------- final: softmax over scores, weighted rowsum ----------------
__global__ __launch_bounds__(1024) void final_kernel(
    const float* __restrict__ scores, const float* __restrict__ rowsum,
    float* __restrict__ out)
{
  __shared__ float red[16], red2[16];
  const int t = threadIdx.x;
  const int lane = t & 63, wid = t >> 6;
  float s[8];
  float m = -3.4e38f;
  #pragma unroll
  for (int i = 0; i < 8; ++i) { s[i] = scores[t + i * 1024]; m = fmaxf(m, s[i]); }
  #pragma unroll
  for (int off = 1; off < 64; off <<= 1) m = fmaxf(m, __shfl_xor(m, off));
  if (lane == 0) red[wid] = m;
  __syncthreads();
  #pragma unroll
  for (int i = 0; i < 16; ++i) m = fmaxf(m, red[i]);
  __syncthreads();

  float se = 0.f, sr = 0.f;
  #pragma unroll
  for (int i = 0; i < 8; ++i) {
    float e = __expf(s[i] - m);
    se += e;
    sr += e * rowsum[t + i * 1024];
  }
  #pragma unroll
  for (int off = 1; off < 64; off <<= 1) { se += __shfl_xor(se, off); sr += __shfl_xor(sr, off); }
  if (lane == 0) { red[wid] = se; red2[wid] = sr; }
  __syncthreads();
  if (t == 0) {
    float tse = 0.f, tsr = 0.f;
    for (int i = 0; i < 16; ++i) { tse += red[i]; tsr += red2[i]; }
    out[0] = tsr / tse;
  }
}

extern "C" void kernel_launch(void* const* d_in, const int* in_sizes, int n_in,
                              void* d_out, int out_size, void* d_ws, size_t ws_size,
                              hipStream_t stream)
{
  const float* x   = (const float*)d_in[0];
  const float* Wm  = (const float*)d_in[1];
  const float* bmv = (const float*)d_in[2];
  const float* u   = (const float*)d_in[3];
  const float* v   = (const float*)d_in[4];
  const float* wv  = (const float*)d_in[5];
  float* out = (float*)d_out;

  if (ws_size < WS_NEED) return;

  char* ws = (char*)d_ws;
  _Float16* xh     = (_Float16*)(ws + OFF_XH);
  _Float16* wh     = (_Float16*)(ws + OFF_WH);
  _Float16* uvh    = (_Float16*)(ws + OFF_UVH);
  _Float16* predsh = (_Float16*)(ws + OFF_PH);
  float*    scores = (float*)(ws + OFF_SC);
  float*    rowsum = (float*)(ws + OFF_RS);

  prep_kernel<<<2048, 256, 0, stream>>>(x, Wm, u, v, xh, wh, uvh, scores, rowsum);
  gemm1_kernel<<<dim3(32, 8), 512, 0, stream>>>(xh, wh, bmv, out, predsh, rowsum);
  gemm2_kernel<<<dim3(128, 4), 256, 0, stream>>>(predsh, uvh, wv, scores);
  final_kernel<<<1, 1024, 0, stream>>>(scores, rowsum, out + (size_t)B_ * C_);
}